// Round 2
// baseline (4363.067 us; speedup 1.0000x reference)
//
#include <hip/hip_runtime.h>
#include <math.h>

#define B_SZ 64
#define T_IN 80
#define H_SZ 256
#define V_SZ 6144
#define L_DEC 30
#define G4 1024
#define SYMBASE (B_SZ * L_DEC * V_SZ)

__device__ __forceinline__ float sigf(float x) { return 1.f / (1.f + expf(-x)); }

// ---- device-scope grid barrier (ticket-based; counter zeroed each launch) ----
__device__ __forceinline__ void gridbar(unsigned* ctr, unsigned nblk) {
    __syncthreads();
    if (threadIdx.x == 0) {
        __threadfence();  // release: write back this XCD's L2
        unsigned ticket = __hip_atomic_fetch_add(ctr, 1u, __ATOMIC_ACQ_REL,
                                                 __HIP_MEMORY_SCOPE_AGENT) + 1u;
        unsigned target = ((ticket + nblk - 1u) / nblk) * nblk;
        while (__hip_atomic_load(ctr, __ATOMIC_RELAXED, __HIP_MEMORY_SCOPE_AGENT) < target)
            __builtin_amdgcn_s_sleep(1);
        __threadfence();  // acquire: invalidate L1/L2 before reading peers' data
    }
    __syncthreads();
}

// stage h[64][256] global -> LDS with 16B-slot XOR swizzle (bank-conflict fix)
__device__ __forceinline__ void stage_h(float* hs, const float* hin, int tid) {
    const float4* src = (const float4*)hin;
    float4* dst = (float4*)hs;
#pragma unroll
    for (int i = tid; i < 4096; i += 256) {
        int bb = i >> 6, s = i & 63;
        dst[(bb << 6) + (s ^ (bb & 7))] = src[i];
    }
}

// monotone float->uint pack with first-index tie-break in low bits
__device__ __forceinline__ unsigned long long packmax(float v, int idx) {
    unsigned u = __float_as_uint(v);
    u = (u & 0x80000000u) ? ~u : (u | 0x80000000u);
    return ((unsigned long long)u << 32) | (unsigned)(0x7FFFFFFF - idx);
}

// ---------------- bias sums ----------------
__global__ void biasum(const float* a1, const float* b1, const float* a2, const float* b2,
                       float* o1, float* o2) {
    int i = blockIdx.x * 256 + threadIdx.x;
    if (i < G4) { o1[i] = a1[i] + b1[i]; o2[i] = a2[i] + b2[i]; }
}

// ---------------- init: zero h0 + barrier counters ----------------
__global__ void init0(float* hb0, unsigned* ctrE, unsigned* ctrD) {
    int i = blockIdx.x * 256 + threadIdx.x;
    if (i < 16384) hb0[i] = 0.f;
    if (i == 0) { *ctrE = 0u; *ctrD = 0u; }
}

// ---------------- tiled fp32 GEMM: C[M][N] = A[M][K] * W[N][K]^T + bias[N] ----
// BM=64, BN=128, BK=16, 256 threads, 4x8 micro-tile (grid 640/768 blocks)
__global__ __launch_bounds__(256) void gemm_rr(const float* __restrict__ A,
                                               const float* __restrict__ W,
                                               const float* __restrict__ bias,
                                               float* __restrict__ C,
                                               int M, int N, int K) {
    __shared__ __align__(16) float As[16][68];    // pad: 2-way max on write
    __shared__ __align__(16) float Bs[16][132];
    const int tid = threadIdx.x;
    const int tx = tid & 15, ty = tid >> 4;
    const int m0 = blockIdx.y * 64, n0 = blockIdx.x * 128;
    const int a_m = tid >> 2, a_k = (tid & 3) * 4;
    const int b_n = tid >> 1, b_k = (tid & 1) * 8;

    float acc[4][8];
#pragma unroll
    for (int r = 0; r < 4; ++r)
#pragma unroll
        for (int c = 0; c < 8; ++c) acc[r][c] = 0.f;

    for (int k0 = 0; k0 < K; k0 += 16) {
        float4 av  = *(const float4*)(A + (size_t)(m0 + a_m) * K + k0 + a_k);
        float4 bv0 = *(const float4*)(W + (size_t)(n0 + b_n) * K + k0 + b_k);
        float4 bv1 = *(const float4*)(W + (size_t)(n0 + b_n) * K + k0 + b_k + 4);
        __syncthreads();
        As[a_k + 0][a_m] = av.x; As[a_k + 1][a_m] = av.y;
        As[a_k + 2][a_m] = av.z; As[a_k + 3][a_m] = av.w;
        Bs[b_k + 0][b_n] = bv0.x; Bs[b_k + 1][b_n] = bv0.y;
        Bs[b_k + 2][b_n] = bv0.z; Bs[b_k + 3][b_n] = bv0.w;
        Bs[b_k + 4][b_n] = bv1.x; Bs[b_k + 5][b_n] = bv1.y;
        Bs[b_k + 6][b_n] = bv1.z; Bs[b_k + 7][b_n] = bv1.w;
        __syncthreads();
#pragma unroll
        for (int kk = 0; kk < 16; ++kk) {
            float4 a0 = *(const float4*)&As[kk][ty * 4];
            float4 b0 = *(const float4*)&Bs[kk][tx * 8];
            float4 b1 = *(const float4*)&Bs[kk][tx * 8 + 4];
            float ar[4] = {a0.x, a0.y, a0.z, a0.w};
            float br[8] = {b0.x, b0.y, b0.z, b0.w, b1.x, b1.y, b1.z, b1.w};
#pragma unroll
            for (int r = 0; r < 4; ++r)
#pragma unroll
                for (int c = 0; c < 8; ++c)
                    acc[r][c] = fmaf(ar[r], br[c], acc[r][c]);
        }
    }
#pragma unroll
    for (int r = 0; r < 4; ++r) {
        float* Crow = C + (size_t)(m0 + ty * 4 + r) * N + n0 + tx * 8;
#pragma unroll
        for (int c = 0; c < 8; ++c)
            Crow[c] = acc[r][c] + bias[n0 + tx * 8 + c];
    }
}

// ---------------- step-0 outputs: dec_o0 broadcast + SOS symbols ----------------
__global__ __launch_bounds__(256) void dec0(const float* __restrict__ embed,
                                            const float* __restrict__ Wout,
                                            const float* __restrict__ bout,
                                            float* __restrict__ out) {
    __shared__ float es[256];
    int tid = threadIdx.x;
    int v = blockIdx.x * 256 + tid;
    es[tid] = embed[256 + tid];  // row SOS=1
    __syncthreads();
    float a = 0.f, a2 = 0.f;
    const float* wr = Wout + (size_t)v * 256;
    for (int k = 0; k < 256; k += 8) {
        float4 w0 = *(const float4*)(wr + k);
        float4 w1 = *(const float4*)(wr + k + 4);
        a  = fmaf(es[k+0],w0.x,fmaf(es[k+1],w0.y,fmaf(es[k+2],w0.z,fmaf(es[k+3],w0.w,a))));
        a2 = fmaf(es[k+4],w1.x,fmaf(es[k+5],w1.y,fmaf(es[k+6],w1.z,fmaf(es[k+7],w1.w,a2))));
    }
    float lg = a + a2 + bout[v];
    for (int b = 0; b < B_SZ; ++b) out[(size_t)b * L_DEC * V_SZ + v] = lg;
    if (blockIdx.x == 0 && tid < B_SZ) out[SYMBASE + tid * L_DEC] = 1.0f;
}

// ---------------- persistent encoder: 80 LSTM1 steps, 1 kernel ----------------
// 64 blocks x 256 thr; block owns 4 hidden units (16 gate rows); lane=batch, wave=gate
__global__ __launch_bounds__(256) void enc_pers(const float* __restrict__ Whh,  // [1024][256]
                                                const float* __restrict__ X1,   // [5120][1024]
                                                float* __restrict__ hb,         // [2][16384]
                                                float* __restrict__ cdec,       // [16384]
                                                unsigned* __restrict__ ctr) {
    __shared__ float hs[16384];
    __shared__ float gbuf[16][64];   // [gate*4+unit][batch]
    __shared__ float cst[256];       // [unit*64+batch]
    const int tid = threadIdx.x;
    const int b = tid & 63;
    const int g = tid >> 6;
    const int u0 = blockIdx.x << 2;
    cst[tid] = 0.f;                  // same thread reads it later: no sync needed
    const int rbase = __builtin_amdgcn_readfirstlane(g * 256 + u0);
    const float* wr0 = Whh + (size_t)rbase * 256;
    const float* wr1 = wr0 + 256;
    const float* wr2 = wr0 + 512;
    const float* wr3 = wr0 + 768;
    const int bx = b & 7;

    for (int t = 0; t < T_IN; ++t) {
        const float* hin = hb + ((t & 1) << 14);
        float* hout = hb + (((t + 1) & 1) << 14);
        stage_h(hs, hin, tid);
        const float* xr = X1 + ((size_t)(b * T_IN + t) << 10) + rbase;
        float x0 = xr[0], x1 = xr[1], x2 = xr[2], x3 = xr[3];
        __syncthreads();

        float a0 = 0.f, a1 = 0.f, a2 = 0.f, a3 = 0.f;
        const float4* hrow = (const float4*)hs + (b << 6);
#pragma unroll 4
        for (int k = 0; k < 256; k += 4) {
            float4 hv = hrow[(k >> 2) ^ bx];
            float4 w0 = *(const float4*)(wr0 + k);
            float4 w1 = *(const float4*)(wr1 + k);
            float4 w2 = *(const float4*)(wr2 + k);
            float4 w3 = *(const float4*)(wr3 + k);
            a0 = fmaf(hv.x,w0.x,fmaf(hv.y,w0.y,fmaf(hv.z,w0.z,fmaf(hv.w,w0.w,a0))));
            a1 = fmaf(hv.x,w1.x,fmaf(hv.y,w1.y,fmaf(hv.z,w1.z,fmaf(hv.w,w1.w,a1))));
            a2 = fmaf(hv.x,w2.x,fmaf(hv.y,w2.y,fmaf(hv.z,w2.z,fmaf(hv.w,w2.w,a2))));
            a3 = fmaf(hv.x,w3.x,fmaf(hv.y,w3.y,fmaf(hv.z,w3.z,fmaf(hv.w,w3.w,a3))));
        }
        gbuf[(g << 2) + 0][b] = a0 + x0;
        gbuf[(g << 2) + 1][b] = a1 + x1;
        gbuf[(g << 2) + 2][b] = a2 + x2;
        gbuf[(g << 2) + 3][b] = a3 + x3;
        __syncthreads();
        {   // update: wave index = unit index j, lane = batch
            int j = g, b2 = b;
            float gi = gbuf[0 + j][b2];
            float gf = gbuf[4 + j][b2];
            float gg = gbuf[8 + j][b2];
            float go = gbuf[12 + j][b2];
            float cn = sigf(gf) * cst[(j << 6) + b2] + sigf(gi) * tanhf(gg);
            cst[(j << 6) + b2] = cn;
            hout[(b2 << 8) + u0 + j] = sigf(go) * tanhf(cn);
            if (t == T_IN - 1) cdec[(b2 << 8) + u0 + j] = cn;
        }
        if (t != T_IN - 1) gridbar(ctr, 64);
    }
}

// ---------------- persistent decoder: 29 steps, 1 kernel ----------------
// 256 blocks x 256 thr; block owns 1 LSTM2 unit + 24 logit columns
__global__ __launch_bounds__(256) void dec_pers(const float* __restrict__ Whh,   // [1024][256]
                                                const float* __restrict__ E2,    // [6144][1024]
                                                const float* __restrict__ Wout,  // [6144][256]
                                                const float* __restrict__ bout,  // [6144]
                                                const float* __restrict__ cdec,
                                                float* __restrict__ hb,          // [2][16384]
                                                float* __restrict__ out,
                                                unsigned long long* __restrict__ parts, // [64][256]
                                                unsigned* __restrict__ ctr) {
    __shared__ float hs[16384];
    __shared__ float gbuf[4][64];
    __shared__ float cst[64];
    __shared__ int ssym[64];
    __shared__ unsigned long long pm[4][64];
    const int tid = threadIdx.x;
    const int b = tid & 63;
    const int g = tid >> 6;
    const int u = blockIdx.x;
    if (tid < 64) { cst[tid] = cdec[(tid << 8) + u]; ssym[tid] = 1; }
    const int wrow  = __builtin_amdgcn_readfirstlane(g * 256 + u);
    const int vbase = __builtin_amdgcn_readfirstlane(u * 24 + g * 6);
    const float* w2r = Whh + (size_t)wrow * 256;
    const int bx = b & 7;

    stage_h(hs, hb, tid);   // h_in for l=0 is hb[0] (encoder final)
    __syncthreads();

    for (int l = 0; l < L_DEC - 1; ++l) {
        float* hout = hb + (((l + 1) & 1) << 14);
        // --- LSTM2: gates = E2[sym] + h @ Whh2^T ---
        float xg = E2[((size_t)ssym[b] << 10) + wrow];
        float aa = 0.f, ab = 0.f;
        const float4* hrow = (const float4*)hs + (b << 6);
#pragma unroll 4
        for (int k = 0; k < 256; k += 8) {
            float4 hv0 = hrow[((k >> 2) + 0) ^ bx];
            float4 hv1 = hrow[((k >> 2) + 1) ^ bx];
            float4 w0 = *(const float4*)(w2r + k);
            float4 w1 = *(const float4*)(w2r + k + 4);
            aa = fmaf(hv0.x,w0.x,fmaf(hv0.y,w0.y,fmaf(hv0.z,w0.z,fmaf(hv0.w,w0.w,aa))));
            ab = fmaf(hv1.x,w1.x,fmaf(hv1.y,w1.y,fmaf(hv1.z,w1.z,fmaf(hv1.w,w1.w,ab))));
        }
        gbuf[g][b] = aa + ab + xg;
        __syncthreads();
        if (tid < 64) {
            float cn = sigf(gbuf[1][tid]) * cst[tid] + sigf(gbuf[0][tid]) * tanhf(gbuf[2][tid]);
            cst[tid] = cn;
            hout[(tid << 8) + u] = sigf(gbuf[3][tid]) * tanhf(cn);
        }
        gridbar(ctr, 256);

        // --- logits: 24 cols/block; stage h2 once (it is next step's h_in too) ---
        stage_h(hs, hout, tid);
        __syncthreads();
        float acc[6] = {0.f, 0.f, 0.f, 0.f, 0.f, 0.f};
#pragma unroll 2
        for (int k = 0; k < 256; k += 4) {
            float4 hv = hrow[(k >> 2) ^ bx];
#pragma unroll
            for (int c = 0; c < 6; ++c) {
                float4 w = *(const float4*)(Wout + (size_t)(vbase + c) * 256 + k);
                acc[c] = fmaf(hv.x,w.x,fmaf(hv.y,w.y,fmaf(hv.z,w.z,fmaf(hv.w,w.w,acc[c]))));
            }
        }
        unsigned long long best = 0ull;
        float* orow = out + (size_t)(b * L_DEC + l + 1) * V_SZ + vbase;
#pragma unroll
        for (int c = 0; c < 6; ++c) {
            float lg = acc[c] + bout[vbase + c];
            orow[c] = lg;
            unsigned long long p = packmax(lg, vbase + c);
            if (p > best) best = p;
        }
        pm[g][b] = best;
        __syncthreads();
        if (tid < 64) {
            unsigned long long m = pm[0][tid];
            if (pm[1][tid] > m) m = pm[1][tid];
            if (pm[2][tid] > m) m = pm[2][tid];
            if (pm[3][tid] > m) m = pm[3][tid];
            parts[((size_t)tid << 8) + u] = m;
        }
        gridbar(ctr, 256);

        // --- argmax finalize (redundant per block: avoids a 3rd barrier) ---
        {
            int bq = tid >> 2, q = tid & 3;
            const unsigned long long* pr = parts + ((size_t)bq << 8) + (q << 6);
            unsigned long long m = 0ull;
#pragma unroll 8
            for (int j = 0; j < 64; ++j) { unsigned long long p = pr[j]; if (p > m) m = p; }
#pragma unroll
            for (int off = 1; off < 4; off <<= 1) {
                unsigned long long o = (unsigned long long)__shfl_xor((long long)m, off);
                if (o > m) m = o;
            }
            if (q == 0) {
                int idx = (int)(0x7FFFFFFFu - (unsigned)(m & 0xFFFFFFFFu));
                ssym[bq] = idx;
                if (blockIdx.x == (unsigned)bq)
                    out[SYMBASE + bq * L_DEC + l + 1] = (float)idx;
            }
        }
        __syncthreads();
    }
}

extern "C" void kernel_launch(void* const* d_in, const int* in_sizes, int n_in,
                              void* d_out, int out_size, void* d_ws, size_t ws_size,
                              hipStream_t stream) {
    const float* input = (const float*)d_in[0];
    // d_in[1] target_lengths: all == L_DEC, unused
    const float* embed = (const float*)d_in[2];
    const float* W_out = (const float*)d_in[3];
    const float* b_out = (const float*)d_in[4];
    const float* W_ih1 = (const float*)d_in[5];
    const float* W_hh1 = (const float*)d_in[6];
    const float* b_ih1 = (const float*)d_in[7];
    const float* b_hh1 = (const float*)d_in[8];
    const float* W_ih2 = (const float*)d_in[9];
    const float* W_hh2 = (const float*)d_in[10];
    const float* b_ih2 = (const float*)d_in[11];
    const float* b_hh2 = (const float*)d_in[12];
    float* out = (float*)d_out;

    float* ws = (float*)d_ws;
    float* X1 = ws;   ws += 5120 * 1024;
    float* E2 = ws;   ws += 6144 * 1024;
    float* hb = ws;   ws += 2 * 16384;
    float* cdec = ws; ws += 16384;
    float* bs1 = ws;  ws += 1024;
    float* bs2 = ws;  ws += 1024;
    unsigned long long* parts = (unsigned long long*)ws; ws += 2 * 16384;
    unsigned* ctrE = (unsigned*)ws; ws += 64;
    unsigned* ctrD = (unsigned*)ws; ws += 64;
    if (ws_size < (size_t)((float*)ws - (float*)d_ws) * 4) return;

    biasum<<<4, 256, 0, stream>>>(b_ih1, b_hh1, b_ih2, b_hh2, bs1, bs2);
    init0<<<64, 256, 0, stream>>>(hb, ctrE, ctrD);
    // X1 = input @ W_ih1^T + (b_ih1+b_hh1) : [5120 x 1024], K=4096
    gemm_rr<<<dim3(8, 80), 256, 0, stream>>>(input, W_ih1, bs1, X1, 5120, 1024, 4096);
    // E2 = embed @ W_ih2^T + (b_ih2+b_hh2) : [6144 x 1024], K=256
    gemm_rr<<<dim3(8, 96), 256, 0, stream>>>(embed, W_ih2, bs2, E2, 6144, 1024, 256);
    dec0<<<24, 256, 0, stream>>>(embed, W_out, b_out, out);
    enc_pers<<<64, 256, 0, stream>>>(W_hh1, X1, hb, cdec, ctrE);
    dec_pers<<<256, 256, 0, stream>>>(W_hh2, E2, W_out, b_out, cdec, hb, out, parts, ctrD);
}

// Round 3
// 2275.164 us; speedup vs baseline: 1.9177x; 1.9177x over previous
//
#include <hip/hip_runtime.h>
#include <math.h>

#define B_SZ 64
#define T_IN 80
#define H_SZ 256
#define V_SZ 6144
#define L_DEC 30
#define SYMBASE (B_SZ * L_DEC * V_SZ)
#define NDB 128            // decoder blocks
#define SLOT_STRIDE 32     // barrier slot padding (ints, 128B)

typedef unsigned long long u64;

__device__ __forceinline__ float sigf(float x) { return 1.f / (1.f + expf(-x)); }

__device__ __forceinline__ void fma4(float4& a, float s, float4 w) {
    a.x = fmaf(s, w.x, a.x); a.y = fmaf(s, w.y, a.y);
    a.z = fmaf(s, w.z, a.z); a.w = fmaf(s, w.w, a.w);
}
__device__ __forceinline__ float4 add4(float4 a, float4 b) {
    return make_float4(a.x + b.x, a.y + b.y, a.z + b.z, a.w + b.w);
}
// monotone float->uint pack, first-index tie-break in low bits
__device__ __forceinline__ u64 packmax(float v, int idx) {
    unsigned u = __float_as_uint(v);
    u = (u & 0x80000000u) ? ~u : (u | 0x80000000u);
    return ((u64)u << 32) | (unsigned)(0x7FFFFFFF - idx);
}
// LDS float4-slot swizzle for h[64][256]: slot s of batch b -> s ^ (b&7)
__device__ __forceinline__ int hslot(int b, int s) { return (b << 6) + (s ^ (b & 7)); }

// ---------------- bias sums ----------------
__global__ void biasum(const float* a1, const float* b1, const float* a2, const float* b2,
                       float* o1, float* o2) {
    int i = blockIdx.x * 256 + threadIdx.x;
    if (i < 1024) { o1[i] = a1[i] + b1[i]; o2[i] = a2[i] + b2[i]; }
}

// ---------------- init: zero barrier slots ----------------
__global__ void init0(int* slots) {
    int i = blockIdx.x * 256 + threadIdx.x;      // 16*256 = 4096
    slots[i] = 0;
}

// ---------------- pack [1024][256] -> gate-float4 [256 k][256 u] ----------------
// Wq[k*256+u] = {W[u][k], W[u+256][k], W[u+512][k], W[u+768][k]}
__global__ __launch_bounds__(256) void packW(const float* __restrict__ W,
                                             float4* __restrict__ Wq) {
    int idx = blockIdx.x * 256 + threadIdx.x;    // 65536
    int u = idx & 255, k = idx >> 8;
    Wq[k * 256 + u] = make_float4(W[(size_t)u * 256 + k],
                                  W[(size_t)(u + 256) * 256 + k],
                                  W[(size_t)(u + 512) * 256 + k],
                                  W[(size_t)(u + 768) * 256 + k]);
}

// ---------------- tiled fp32 GEMM: C = A[M][K] * W[N][K]^T + bias, gate-permuted cols ----
// BM=64, BN=128, BK=16, 256 threads, 4x8 micro-tile
template <int PERM>
__global__ __launch_bounds__(256) void gemm_rr(const float* __restrict__ A,
                                               const float* __restrict__ W,
                                               const float* __restrict__ bias,
                                               float* __restrict__ C,
                                               int M, int N, int K) {
    __shared__ __align__(16) float As[16][68];
    __shared__ __align__(16) float Bs[16][132];
    const int tid = threadIdx.x;
    const int tx = tid & 15, ty = tid >> 4;
    const int m0 = blockIdx.y * 64, n0 = blockIdx.x * 128;
    const int a_m = tid >> 2, a_k = (tid & 3) * 4;
    const int b_n = tid >> 1, b_k = (tid & 1) * 8;

    float acc[4][8];
#pragma unroll
    for (int r = 0; r < 4; ++r)
#pragma unroll
        for (int c = 0; c < 8; ++c) acc[r][c] = 0.f;

    for (int k0 = 0; k0 < K; k0 += 16) {
        float4 av  = *(const float4*)(A + (size_t)(m0 + a_m) * K + k0 + a_k);
        float4 bv0 = *(const float4*)(W + (size_t)(n0 + b_n) * K + k0 + b_k);
        float4 bv1 = *(const float4*)(W + (size_t)(n0 + b_n) * K + k0 + b_k + 4);
        __syncthreads();
        As[a_k + 0][a_m] = av.x; As[a_k + 1][a_m] = av.y;
        As[a_k + 2][a_m] = av.z; As[a_k + 3][a_m] = av.w;
        Bs[b_k + 0][b_n] = bv0.x; Bs[b_k + 1][b_n] = bv0.y;
        Bs[b_k + 2][b_n] = bv0.z; Bs[b_k + 3][b_n] = bv0.w;
        Bs[b_k + 4][b_n] = bv1.x; Bs[b_k + 5][b_n] = bv1.y;
        Bs[b_k + 6][b_n] = bv1.z; Bs[b_k + 7][b_n] = bv1.w;
        __syncthreads();
#pragma unroll
        for (int kk = 0; kk < 16; ++kk) {
            float4 a0 = *(const float4*)&As[kk][ty * 4];
            float4 b0 = *(const float4*)&Bs[kk][tx * 8];
            float4 b1 = *(const float4*)&Bs[kk][tx * 8 + 4];
            float ar[4] = {a0.x, a0.y, a0.z, a0.w};
            float br[8] = {b0.x, b0.y, b0.z, b0.w, b1.x, b1.y, b1.z, b1.w};
#pragma unroll
            for (int r = 0; r < 4; ++r)
#pragma unroll
                for (int c = 0; c < 8; ++c)
                    acc[r][c] = fmaf(ar[r], br[c], acc[r][c]);
        }
    }
#pragma unroll
    for (int r = 0; r < 4; ++r) {
        float* Crow = C + (size_t)(m0 + ty * 4 + r) * N;
#pragma unroll
        for (int c = 0; c < 8; ++c) {
            int j = n0 + tx * 8 + c;
            int jp = PERM ? ((j & 255) * 4 + (j >> 8)) : j;
            Crow[jp] = acc[r][c] + bias[j];
        }
    }
}

// ---------------- step-0 outputs: dec_o0 broadcast + SOS symbols ----------------
__global__ __launch_bounds__(256) void dec0(const float* __restrict__ embed,
                                            const float* __restrict__ Wout,
                                            const float* __restrict__ bout,
                                            float* __restrict__ out) {
    __shared__ float es[256];
    int tid = threadIdx.x;
    int v = blockIdx.x * 256 + tid;
    es[tid] = embed[256 + tid];  // row SOS=1
    __syncthreads();
    float a = 0.f, a2 = 0.f;
    const float* wr = Wout + (size_t)v * 256;
    for (int k = 0; k < 256; k += 8) {
        float4 w0 = *(const float4*)(wr + k);
        float4 w1 = *(const float4*)(wr + k + 4);
        a  = fmaf(es[k+0],w0.x,fmaf(es[k+1],w0.y,fmaf(es[k+2],w0.z,fmaf(es[k+3],w0.w,a))));
        a2 = fmaf(es[k+4],w1.x,fmaf(es[k+5],w1.y,fmaf(es[k+6],w1.z,fmaf(es[k+7],w1.w,a2))));
    }
    float lg = a + a2 + bout[v];
    for (int b = 0; b < B_SZ; ++b) out[(size_t)b * L_DEC * V_SZ + v] = lg;
    if (blockIdx.x == 0 && tid < B_SZ) out[SYMBASE + tid * L_DEC] = 1.0f;
}

// ---------------- encoder: one block per batch element, zero sync ----------------
// 64 blocks x 1024 threads. h,c live in LDS for all 80 steps.
__global__ __launch_bounds__(1024) void enc_fused(const float4* __restrict__ Wq1,  // [256k][256u]
                                                  const float4* __restrict__ Xq,   // [5120][256] f4
                                                  float* __restrict__ hb0,         // h_final out
                                                  float* __restrict__ cfin) {
    __shared__ float hs[H_SZ];
    __shared__ float cs[H_SZ];
    __shared__ __align__(16) float4 pp[4][H_SZ];
    const int tid = threadIdx.x;
    const int b = blockIdx.x;
    const int u = tid & 255;
    const int q = tid >> 8;              // k-quarter 0..3
    if (tid < 256) { hs[tid] = 0.f; cs[tid] = 0.f; }
    __syncthreads();

    for (int t = 0; t < T_IN; ++t) {
        float4 acc = {0.f, 0.f, 0.f, 0.f};
        const float4* wp = Wq1 + (size_t)(q * 64) * 256 + u;
        const float4* hp = (const float4*)hs + q * 16;
#pragma unroll 4
        for (int i = 0; i < 16; ++i) {
            float4 hv = hp[i];
            fma4(acc, hv.x, wp[0]);
            fma4(acc, hv.y, wp[256]);
            fma4(acc, hv.z, wp[512]);
            fma4(acc, hv.w, wp[768]);
            wp += 1024;
        }
        pp[q][u] = acc;
        __syncthreads();
        if (tid < 256) {
            float4 g = add4(add4(pp[0][tid], pp[1][tid]), add4(pp[2][tid], pp[3][tid]));
            float4 xg = Xq[(size_t)(b * T_IN + t) * 256 + tid];
            float gi = g.x + xg.x, gf = g.y + xg.y, gg = g.z + xg.z, go = g.w + xg.w;
            float cn = sigf(gf) * cs[tid] + sigf(gi) * tanhf(gg);
            float hn = sigf(go) * tanhf(cn);
            cs[tid] = cn;
            hs[tid] = hn;
            if (t == T_IN - 1) {
                hb0[b * 256 + tid] = hn;
                cfin[b * 256 + tid] = cn;
            }
        }
        __syncthreads();
    }
}

// ---------------- zero-atomic arrival barrier (no fences; data uses sc1 ops) ----------
__device__ __forceinline__ void bar(int* slots, int x, int phase, int tid) {
    __syncthreads();   // compiler drains vmcnt/lgkmcnt before s_barrier -> sc1 stores done
    if (tid == 0)
        __hip_atomic_store(&slots[x * SLOT_STRIDE], phase,
                           __ATOMIC_RELAXED, __HIP_MEMORY_SCOPE_AGENT);
    if (tid < 64) {
        const int j0 = tid * 2, j1 = tid * 2 + 1;
        while (true) {
            int v0 = __hip_atomic_load(&slots[j0 * SLOT_STRIDE],
                                       __ATOMIC_RELAXED, __HIP_MEMORY_SCOPE_AGENT);
            int v1 = __hip_atomic_load(&slots[j1 * SLOT_STRIDE],
                                       __ATOMIC_RELAXED, __HIP_MEMORY_SCOPE_AGENT);
            if (!__any(v0 < phase || v1 < phase)) break;
            __builtin_amdgcn_s_sleep(4);
        }
    }
    __syncthreads();
}

// ---------------- decoder: 128 blocks x 512 threads ----------------
// Block x owns LSTM2 units {2x, 2x+1} (all batches) + logit cols [48x, 48x+48).
__global__ __launch_bounds__(512) void dec_fused(
    const float4* __restrict__ Wq2,    // Whh2 packed [256k][256u]
    const float4* __restrict__ Wxq2,   // W_ih2 packed [256k][256u]
    const float4* __restrict__ embed4, // [V][64] f4
    const float* __restrict__ Wout,    // [6144][256]
    const float* __restrict__ bout,
    const float* __restrict__ bs2,     // b_ih2+b_hh2 [1024]
    const float* __restrict__ hb,      // [2][16384]; hb[0] holds h_enc at entry
    const float* __restrict__ cfin,
    u64* __restrict__ parts,           // [64 b][128 x]
    int* __restrict__ slots,
    float* __restrict__ out) {
    __shared__ __align__(16) float4 hs4[4096];   // swizzled h[64][256]
    __shared__ __align__(16) float4 gp[4][2][64];
    __shared__ u64 pm[8][64];
    __shared__ float cs[2][64];
    __shared__ int ssym[64];
    const int tid = threadIdx.x;
    const int x = blockIdx.x;
    const int lane = tid & 63;

    {   // init: stage h_enc (plain loads: kernel-boundary coherence), c, sym
        const float4* hf4 = (const float4*)hb;
#pragma unroll
        for (int i = tid; i < 4096; i += 512) {
            int b = i >> 6, s = i & 63;
            hs4[hslot(b, s)] = hf4[i];
        }
        if (tid < 128) { int uu = tid >> 6; cs[uu][lane] = cfin[lane * 256 + x * 2 + uu]; }
        if (tid < 64) ssym[tid] = 1;
    }
    __syncthreads();

    int phase = 0;
    for (int l = 0; l < L_DEC - 1; ++l) {
        float* hnext = (float*)hb + (((l + 1) & 1) << 14);
        // ---- LSTM2 gates: h-part + x-part (embed[sym] @ W_ih2^T) ----
        {
            const int b = lane;
            const int uu = (tid >> 6) & 1;
            const int ks = tid >> 7;                       // 0..3
            const int u  = __builtin_amdgcn_readfirstlane(x * 2 + uu);
            const int k0 = __builtin_amdgcn_readfirstlane(ks * 64);
            const int row = ssym[b];
            float4 acc = {0.f, 0.f, 0.f, 0.f};
            const float4* wp  = Wq2  + (size_t)k0 * 256 + u;
            const float4* wxp = Wxq2 + (size_t)k0 * 256 + u;
            const float4* ep  = embed4 + (size_t)row * 64 + (k0 >> 2);
#pragma unroll 4
            for (int i = 0; i < 16; ++i) {
                float4 hv = hs4[(b << 6) + (((k0 >> 2) + i) ^ (b & 7))];
                float4 ev = ep[i];
                fma4(acc, hv.x, wp[0]);  fma4(acc, hv.y, wp[256]);
                fma4(acc, hv.z, wp[512]); fma4(acc, hv.w, wp[768]);
                fma4(acc, ev.x, wxp[0]); fma4(acc, ev.y, wxp[256]);
                fma4(acc, ev.z, wxp[512]); fma4(acc, ev.w, wxp[768]);
                wp += 1024; wxp += 1024;
            }
            gp[ks][uu][b] = acc;
        }
        __syncthreads();
        if (tid < 128) {
            const int b = lane, uu = tid >> 6;
            const int u = x * 2 + uu;
            float4 g = add4(add4(gp[0][uu][b], gp[1][uu][b]),
                            add4(gp[2][uu][b], gp[3][uu][b]));
            float gi = g.x + bs2[u];
            float gf = g.y + bs2[u + 256];
            float gg = g.z + bs2[u + 512];
            float go = g.w + bs2[u + 768];
            float cn = sigf(gf) * cs[uu][b] + sigf(gi) * tanhf(gg);
            cs[uu][b] = cn;
            float hn = sigf(go) * tanhf(cn);
            __hip_atomic_store(&hnext[b * 256 + u], hn,
                               __ATOMIC_RELAXED, __HIP_MEMORY_SCOPE_AGENT);
        }
        ++phase; bar(slots, x, phase, tid);          // barrier A: h' visible

        // ---- stage h_{l+1} (sc1 loads: bypass stale per-XCD L2) ----
        {
            const u64* hp = (const u64*)hnext;
#pragma unroll
            for (int i = tid; i < 4096; i += 512) {
                int b = i >> 6, s = i & 63;
                u64 lo = __hip_atomic_load(&hp[i * 2],     __ATOMIC_RELAXED, __HIP_MEMORY_SCOPE_AGENT);
                u64 hi = __hip_atomic_load(&hp[i * 2 + 1], __ATOMIC_RELAXED, __HIP_MEMORY_SCOPE_AGENT);
                float4 v;
                v.x = __uint_as_float((unsigned)lo); v.y = __uint_as_float((unsigned)(lo >> 32));
                v.z = __uint_as_float((unsigned)hi); v.w = __uint_as_float((unsigned)(hi >> 32));
                hs4[hslot(b, s)] = v;
            }
        }
        __syncthreads();

        // ---- logits: 6 cols per wave, lane = batch; W rows via wave-uniform s_loads ----
        {
            const int b  = lane;
            const int wv = __builtin_amdgcn_readfirstlane(tid >> 6);   // 0..7
            const int v0 = __builtin_amdgcn_readfirstlane(x * 48 + wv * 6);
            float acc[6] = {0.f, 0.f, 0.f, 0.f, 0.f, 0.f};
            const float* w0 = Wout + (size_t)v0 * 256;
#pragma unroll 2
            for (int k4 = 0; k4 < 64; ++k4) {
                float4 hv = hs4[(b << 6) + (k4 ^ (b & 7))];
#pragma unroll
                for (int c = 0; c < 6; ++c) {
                    float4 w = *(const float4*)(w0 + c * 256 + k4 * 4);
                    acc[c] = fmaf(hv.x, w.x, fmaf(hv.y, w.y,
                             fmaf(hv.z, w.z, fmaf(hv.w, w.w, acc[c]))));
                }
            }
            u64 best = 0ull;
            float* orow = out + (size_t)(b * L_DEC + l + 1) * V_SZ + v0;
#pragma unroll
            for (int c = 0; c < 6; ++c) {
                float lg = acc[c] + bout[v0 + c];
                orow[c] = lg;
                u64 p = packmax(lg, v0 + c);
                if (p > best) best = p;
            }
            pm[wv][b] = best;
        }
        __syncthreads();
        if (tid < 64) {
            u64 m = pm[0][tid];
#pragma unroll
            for (int j = 1; j < 8; ++j) if (pm[j][tid] > m) m = pm[j][tid];
            __hip_atomic_store(&parts[(size_t)tid * NDB + x], m,
                               __ATOMIC_RELAXED, __HIP_MEMORY_SCOPE_AGENT);
        }
        ++phase; bar(slots, x, phase, tid);          // barrier B: partials visible

        // ---- global argmax (redundant per block) ----
        {
            const int b = tid & 63, sg = tid >> 6;   // 8 segments of 16
            const u64* pr = parts + (size_t)b * NDB + sg * 16;
            u64 m = 0ull;
#pragma unroll 4
            for (int j = 0; j < 16; ++j) {
                u64 p = __hip_atomic_load(&pr[j], __ATOMIC_RELAXED, __HIP_MEMORY_SCOPE_AGENT);
                if (p > m) m = p;
            }
            pm[sg][b] = m;
        }
        __syncthreads();
        if (tid < 64) {
            u64 m = pm[0][tid];
#pragma unroll
            for (int j = 1; j < 8; ++j) if (pm[j][tid] > m) m = pm[j][tid];
            int idx = (int)(0x7FFFFFFFu - (unsigned)(m & 0xFFFFFFFFu));
            ssym[tid] = idx;
            if (x == tid) out[SYMBASE + tid * L_DEC + l + 1] = (float)idx;
        }
        __syncthreads();
    }
}

extern "C" void kernel_launch(void* const* d_in, const int* in_sizes, int n_in,
                              void* d_out, int out_size, void* d_ws, size_t ws_size,
                              hipStream_t stream) {
    const float* input = (const float*)d_in[0];
    // d_in[1] target_lengths: all == L_DEC, unused
    const float* embed = (const float*)d_in[2];
    const float* W_out = (const float*)d_in[3];
    const float* b_out = (const float*)d_in[4];
    const float* W_ih1 = (const float*)d_in[5];
    const float* W_hh1 = (const float*)d_in[6];
    const float* b_ih1 = (const float*)d_in[7];
    const float* b_hh1 = (const float*)d_in[8];
    const float* W_ih2 = (const float*)d_in[9];
    const float* W_hh2 = (const float*)d_in[10];
    const float* b_ih2 = (const float*)d_in[11];
    const float* b_hh2 = (const float*)d_in[12];
    float* out = (float*)d_out;

    float* ws = (float*)d_ws;
    float* X1q  = ws; ws += 5120 * 1024;   // gate-packed X1
    float* Wq1  = ws; ws += 256 * 1024;    // Whh1 packed
    float* Wq2  = ws; ws += 256 * 1024;    // Whh2 packed
    float* Wxq2 = ws; ws += 256 * 1024;    // W_ih2 packed
    float* hb   = ws; ws += 2 * 16384;     // h double buffer (hb[0] = h_enc handoff)
    float* cfin = ws; ws += 16384;
    float* bs1  = ws; ws += 1024;
    float* bs2  = ws; ws += 1024;
    u64*  parts = (u64*)ws; ws += 2 * 64 * NDB;
    int*  slots = (int*)ws; ws += NDB * SLOT_STRIDE;
    if (ws_size < (size_t)((float*)ws - (float*)d_ws) * 4) return;

    biasum<<<4, 256, 0, stream>>>(b_ih1, b_hh1, b_ih2, b_hh2, bs1, bs2);
    init0<<<16, 256, 0, stream>>>(slots);
    packW<<<256, 256, 0, stream>>>(W_hh1, (float4*)Wq1);
    packW<<<256, 256, 0, stream>>>(W_hh2, (float4*)Wq2);
    packW<<<256, 256, 0, stream>>>(W_ih2, (float4*)Wxq2);
    // X1q = gatepack(input @ W_ih1^T + (b_ih1+b_hh1)) : [5120 x 1024], K=4096
    gemm_rr<1><<<dim3(8, 80), 256, 0, stream>>>(input, W_ih1, bs1, X1q, 5120, 1024, 4096);
    dec0<<<24, 256, 0, stream>>>(embed, W_out, b_out, out);
    enc_fused<<<64, 1024, 0, stream>>>((const float4*)Wq1, (const float4*)X1q, hb, cfin);
    dec_fused<<<NDB, 512, 0, stream>>>((const float4*)Wq2, (const float4*)Wxq2,
                                       (const float4*)embed, W_out, b_out, bs2,
                                       hb, cfin, parts, slots, out);
}